// Round 1
// baseline (2101.287 us; speedup 1.0000x reference)
//
#include <hip/hip_runtime.h>
#include <cmath>
#include <cstdint>
#include <cstddef>

#define NN 16384
#define NE 524288

// ---------------- workspace layout (byte offsets, 16-aligned) ----------------
static constexpr size_t OFF_XW       = 0;         // [NN][8] f32  = 524288 B
static constexpr size_t OFF_HW       = 524288;    // [NN][2] f32  = 131072 B
static constexpr size_t OFF_DINV     = 655360;    // [NN]    f32  =  65536 B
static constexpr size_t OFF_CNT      = 720896;    // [NN]    i32  =  65536 B
static constexpr size_t OFF_ROWSTART = 786432;    // [NN+1]  i32  (pad to 65552->16B align)
static constexpr size_t OFF_CURSOR   = 851984;    // [NN]    i32  =  65536 B
static constexpr size_t OFF_CSR      = 917520;    // [NE]    i32  = 2097152 B
// total ~3.0 MB

__global__ __launch_bounds__(256) void k_zero_cnt(int* __restrict__ cnt) {
    int i = blockIdx.x * 256 + threadIdx.x;
    if (i < NN) cnt[i] = 0;
}

// xw = x @ W1   (M=16384, K=16384, Ncol=8), fp32 streaming GEMM.
// Wave = 8 rows x 8 k-threads; lane = row_local*8 + kt.
__global__ __launch_bounds__(256) void k_gemm1(const float* __restrict__ x,
                                               const float* __restrict__ W1,
                                               float* __restrict__ xw) {
    const int lane = threadIdx.x & 63;
    const int wave = threadIdx.x >> 6;
    const int row  = blockIdx.x * 32 + wave * 8 + (lane >> 3);
    const int kt   = lane & 7;

    const float4* __restrict__ xr = (const float4*)(x + (size_t)row * NN);

    float acc[8];
#pragma unroll
    for (int j = 0; j < 8; ++j) acc[j] = 0.0f;

#pragma unroll 2
    for (int k0 = 0; k0 < NN; k0 += 32) {
        float4 xv = xr[(k0 >> 2) + kt];
        const float4* __restrict__ wr = (const float4*)(W1 + (size_t)(k0 + (kt << 2)) * 8);
#pragma unroll
        for (int i = 0; i < 4; ++i) {
            float xs = (i == 0) ? xv.x : (i == 1) ? xv.y : (i == 2) ? xv.z : xv.w;
            float4 wlo = wr[2 * i];
            float4 whi = wr[2 * i + 1];
            acc[0] += xs * wlo.x; acc[1] += xs * wlo.y;
            acc[2] += xs * wlo.z; acc[3] += xs * wlo.w;
            acc[4] += xs * whi.x; acc[5] += xs * whi.y;
            acc[6] += xs * whi.z; acc[7] += xs * whi.w;
        }
    }

    // reduce across the 8 kt-lanes of this row (xor of low 3 bits stays in-row)
#pragma unroll
    for (int j = 0; j < 8; ++j) {
        acc[j] += __shfl_xor(acc[j], 1);
        acc[j] += __shfl_xor(acc[j], 2);
        acc[j] += __shfl_xor(acc[j], 4);
    }

    if (kt == 0) {
        float4* o = (float4*)(xw + (size_t)row * 8);
        o[0] = make_float4(acc[0], acc[1], acc[2], acc[3]);
        o[1] = make_float4(acc[4], acc[5], acc[6], acc[7]);
    }
}

__global__ __launch_bounds__(256) void k_count(const int* __restrict__ dst, int* __restrict__ cnt) {
    int i = blockIdx.x * 256 + threadIdx.x;
    if (i < NE) atomicAdd(&cnt[dst[i]], 1);
}

// single block: exclusive prefix sum of cnt[NN] -> rowstart[NN+1], cursor copy
__global__ __launch_bounds__(256) void k_scan(const int* __restrict__ cnt,
                                              int* __restrict__ rowstart,
                                              int* __restrict__ cursor) {
    __shared__ int part[256];
    __shared__ int ex[257];
    const int t = threadIdx.x;
    int s = 0;
#pragma unroll 4
    for (int i = 0; i < 64; ++i) s += cnt[t * 64 + i];
    part[t] = s;
    __syncthreads();
    if (t == 0) {
        int run = 0;
        for (int i = 0; i < 256; ++i) { ex[i] = run; run += part[i]; }
        ex[256] = run;
    }
    __syncthreads();
    int base = ex[t];
    for (int i = 0; i < 64; ++i) {
        int idx = t * 64 + i;
        rowstart[idx] = base;
        cursor[idx]   = base;
        base += cnt[idx];
    }
    if (t == 255) rowstart[NN] = ex[256];
}

__global__ __launch_bounds__(256) void k_dinv(const int* __restrict__ cnt, float* __restrict__ dinv) {
    int i = blockIdx.x * 256 + threadIdx.x;
    if (i < NN) dinv[i] = rsqrtf((float)cnt[i] + 1.0f);  // +1 self-loop
}

__global__ __launch_bounds__(256) void k_fill(const int* __restrict__ src,
                                              const int* __restrict__ dst,
                                              int* __restrict__ cursor,
                                              int* __restrict__ csr) {
    int i = blockIdx.x * 256 + threadIdx.x;
    if (i < NE) {
        int d = dst[i];
        int pos = atomicAdd(&cursor[d], 1);
        csr[pos] = src[i];
    }
}

// one wave per node: agg1 + tanh(+b1) fused with h@W2 -> hw[NN][2]
__global__ __launch_bounds__(256) void k_agg1(const float* __restrict__ xw,
                                              const int* __restrict__ rowstart,
                                              const int* __restrict__ csr,
                                              const float* __restrict__ dinv,
                                              const float* __restrict__ b1,
                                              const float* __restrict__ W2,
                                              float* __restrict__ hw) {
    const int lane = threadIdx.x & 63;
    const int wave = threadIdx.x >> 6;
    const int d = blockIdx.x * 4 + wave;
    const int start = rowstart[d];
    const int end   = rowstart[d + 1];

    float acc[8];
#pragma unroll
    for (int j = 0; j < 8; ++j) acc[j] = 0.0f;

    for (int idx = start + lane; idx < end; idx += 64) {
        int s = csr[idx];
        float w = dinv[s];
        const float4* xs = (const float4*)(xw + (size_t)s * 8);
        float4 a = xs[0], b = xs[1];
        acc[0] += a.x * w; acc[1] += a.y * w; acc[2] += a.z * w; acc[3] += a.w * w;
        acc[4] += b.x * w; acc[5] += b.y * w; acc[6] += b.z * w; acc[7] += b.w * w;
    }

#pragma unroll
    for (int m = 1; m < 64; m <<= 1) {
#pragma unroll
        for (int j = 0; j < 8; ++j) acc[j] += __shfl_xor(acc[j], m);
    }

    const float dv = dinv[d];
    const float4* xd = (const float4*)(xw + (size_t)d * 8);
    float4 sa = xd[0], sb = xd[1];
    float h[8];
    h[0] = tanhf((acc[0] + sa.x * dv) * dv + b1[0]);
    h[1] = tanhf((acc[1] + sa.y * dv) * dv + b1[1]);
    h[2] = tanhf((acc[2] + sa.z * dv) * dv + b1[2]);
    h[3] = tanhf((acc[3] + sa.w * dv) * dv + b1[3]);
    h[4] = tanhf((acc[4] + sb.x * dv) * dv + b1[4]);
    h[5] = tanhf((acc[5] + sb.y * dv) * dv + b1[5]);
    h[6] = tanhf((acc[6] + sb.z * dv) * dv + b1[6]);
    h[7] = tanhf((acc[7] + sb.w * dv) * dv + b1[7]);

    if (lane == 0) {
        float hw0 = 0.0f, hw1 = 0.0f;
#pragma unroll
        for (int j = 0; j < 8; ++j) {
            hw0 += h[j] * W2[j * 2 + 0];
            hw1 += h[j] * W2[j * 2 + 1];
        }
        float2* o = (float2*)(hw + (size_t)d * 2);
        *o = make_float2(hw0, hw1);
    }
}

// one wave per node: agg2 + tanh(+b2) + [2->1] head + sigmoid -> out[NN]
__global__ __launch_bounds__(256) void k_agg2(const float* __restrict__ hw,
                                              const int* __restrict__ rowstart,
                                              const int* __restrict__ csr,
                                              const float* __restrict__ dinv,
                                              const float* __restrict__ b2,
                                              const float* __restrict__ Wc,
                                              const float* __restrict__ bc,
                                              float* __restrict__ out) {
    const int lane = threadIdx.x & 63;
    const int wave = threadIdx.x >> 6;
    const int d = blockIdx.x * 4 + wave;
    const int start = rowstart[d];
    const int end   = rowstart[d + 1];

    float a0 = 0.0f, a1 = 0.0f;
    for (int idx = start + lane; idx < end; idx += 64) {
        int s = csr[idx];
        float w = dinv[s];
        float2 v = *(const float2*)(hw + (size_t)s * 2);
        a0 += v.x * w;
        a1 += v.y * w;
    }
#pragma unroll
    for (int m = 1; m < 64; m <<= 1) {
        a0 += __shfl_xor(a0, m);
        a1 += __shfl_xor(a1, m);
    }

    if (lane == 0) {
        float dv = dinv[d];
        float2 self = *(const float2*)(hw + (size_t)d * 2);
        float e0 = tanhf((a0 + self.x * dv) * dv + b2[0]);
        float e1 = tanhf((a1 + self.y * dv) * dv + b2[1]);
        float logit = e0 * Wc[0] + e1 * Wc[1] + bc[0];
        out[d] = 1.0f / (1.0f + expf(-logit));
    }
}

extern "C" void kernel_launch(void* const* d_in, const int* in_sizes, int n_in,
                              void* d_out, int out_size, void* d_ws, size_t ws_size,
                              hipStream_t stream) {
    const float* x   = (const float*)d_in[0];
    const int*   ei  = (const int*)d_in[1];
    const float* W1  = (const float*)d_in[2];
    const float* b1  = (const float*)d_in[3];
    const float* W2  = (const float*)d_in[4];
    const float* b2  = (const float*)d_in[5];
    const float* Wc  = (const float*)d_in[6];
    const float* bc  = (const float*)d_in[7];
    float* out = (float*)d_out;

    const int* src = ei;
    const int* dst = ei + NE;

    char* wsb = (char*)d_ws;
    float* xw       = (float*)(wsb + OFF_XW);
    float* hw       = (float*)(wsb + OFF_HW);
    float* dinv     = (float*)(wsb + OFF_DINV);
    int*   cnt      = (int*)  (wsb + OFF_CNT);
    int*   rowstart = (int*)  (wsb + OFF_ROWSTART);
    int*   cursor   = (int*)  (wsb + OFF_CURSOR);
    int*   csr      = (int*)  (wsb + OFF_CSR);

    // graph structure (cheap, L2-resident)
    k_zero_cnt<<<NN / 256, 256, 0, stream>>>(cnt);
    k_count<<<NE / 256, 256, 0, stream>>>(dst, cnt);
    k_scan<<<1, 256, 0, stream>>>(cnt, rowstart, cursor);
    k_dinv<<<NN / 256, 256, 0, stream>>>(cnt, dinv);
    k_fill<<<NE / 256, 256, 0, stream>>>(src, dst, cursor, csr);

    // dominant kernel: 1 GiB stream of x
    k_gemm1<<<NN / 32, 256, 0, stream>>>(x, W1, xw);

    // per-node aggregations (wave per node)
    k_agg1<<<NN / 4, 256, 0, stream>>>(xw, rowstart, csr, dinv, b1, W2, hw);
    k_agg2<<<NN / 4, 256, 0, stream>>>(hw, rowstart, csr, dinv, b2, Wc, bc, out);
}